// Round 19
// baseline (536.469 us; speedup 1.0000x reference)
//
#include <hip/hip_runtime.h>
#include <hip/hip_bf16.h>

// GNODE fully fused: y' = relu(y@W1+b1)@W2+b2, RK4(3/8) x10 steps (h=0.1),
// out = y@Wl+bl.  N=200000 rows, 128 ch, 64 out ch.
//
// Round 19: 8-WAY channel split.  Law from r10/r15/r18: adding per-wave work
// always loses (regs -> occupancy); r16->r17 showed deeper splits win.  Now:
// block = 512 thr = 8 waves, 16 rows; wave wid owns out-ch [16wid,+16) (one
// MFMA MB block) of both layers:
//   - weights 4+4 A-frags = 32 regs (AGPR-resident), acc 4+4, state y/U/V 12
//   - wave's 4 state elems = HALF a B-frag (j = 4(wid&1)+r of frag wid>>1)
//     -> exchange = 1 ds_write_b64 + 4 ds_read_b128 per matmul
//   - total ~90-100 regs -> ~5 waves/SIMD; matrix demand 5x155cy vs ~550cy
//     per-wave critical path -> pipe approaches saturation.
// Epilogue: all 8 waves write y half-frags; waves 0-3 compute the 64 out-ch.
//
// State recurrences (template<MODE>):
//   M1: U<-k1   M2: V<-k2   M3: U<-U+3(V+k3), V<-U-V+k3   M4: y+=h/8(U+k4)
// Layout identity (mfma_f32_16x16x32_bf16, HW-verified m89):
//   D:      ch = 16*MB + 4*(lane>>4) + r,               batch = lane&15
//   B-frag: ch = 32*kb + 16*(j>>2) + 4*(lane>>4)+(j&3),  batch = lane&15
// => frag[kb][j] = state[8*kb + j]; wave wid owns MB=wid, state elems
//    [4wid, 4wid+4): frag slot wid>>1, half wid&1.  All lane-local.
// Barrier safety: 2 barriers/feval on alternating buffers (argx, hx).

typedef __attribute__((ext_vector_type(8))) short bf16x8;
typedef __attribute__((ext_vector_type(4))) float f32x4;

constexpr float HS = 0.1f;

__device__ __forceinline__ unsigned short bfu(float f) {
    return __builtin_bit_cast(unsigned short, (__bf16)f);   // -> v_cvt_pk_bf16_f32
}
__device__ __forceinline__ bf16x8 bc8(uint4 u) { return __builtin_bit_cast(bf16x8, u); }

#define MFMA_BF16 __builtin_amdgcn_mfma_f32_16x16x32_bf16

// Own quarter-frag (4 elems -> uint2) from fp32 y/U/V, RK4 combo per mode.
template<int M>
__device__ __forceinline__ uint2 build_q(const float (&y)[4], const float (&U)[4],
                                         const float (&V)[4]) {
    unsigned short s[4];
    #pragma unroll
    for (int r = 0; r < 4; ++r) {
        float v;
        if (M == 1)      v = y[r];
        else if (M == 2) v = fmaf(HS * (1.f / 3.f), U[r], y[r]);
        else if (M == 3) v = fmaf(-HS * (1.f / 3.f), U[r], fmaf(HS, V[r], y[r]));
        else             v = fmaf(HS, V[r], y[r]);
        s[r] = bfu(v);
    }
    uint2 o;
    o.x = (unsigned)s[0] | ((unsigned)s[1] << 16);
    o.y = (unsigned)s[2] | ((unsigned)s[3] << 16);
    return o;
}

// One f-eval for this wave's 16-out-ch slice (MB = wid).
template<int M>
__device__ __forceinline__ void feval(const bf16x8 (&w1r)[4], const bf16x8 (&w2r)[4],
                                      const float* __restrict__ sbf1,
                                      const float* __restrict__ sbf2,
                                      uint2* __restrict__ my_arg,
                                      const uint4* __restrict__ abase,
                                      uint2* __restrict__ my_h,
                                      const uint4* __restrict__ hbase,
                                      float (&y)[4], float (&U)[4], float (&V)[4])
{
    // ---- own arg quarter -> LDS; bias init overlaps the barrier
    *my_arg = build_q<M>(y, U, V);
    f32x4 acc = *(const f32x4*)sbf1;
    __syncthreads();
    const bf16x8 a0 = bc8(abase[0]);
    const bf16x8 a1 = bc8(abase[64]);
    const bf16x8 a2 = bc8(abase[128]);
    const bf16x8 a3 = bc8(abase[192]);

    // ---- matmul1: 4 MFMA
    __builtin_amdgcn_s_setprio(1);
    acc = MFMA_BF16(w1r[0], a0, acc, 0, 0, 0);
    acc = MFMA_BF16(w1r[1], a1, acc, 0, 0, 0);
    acc = MFMA_BF16(w1r[2], a2, acc, 0, 0, 0);
    acc = MFMA_BF16(w1r[3], a3, acc, 0, 0, 0);
    __builtin_amdgcn_s_setprio(0);

    // ---- relu -> own h quarter (acc[r] = h ch 16wid+4g+r)
    uint2 hq;
    hq.x = (unsigned)bfu(fmaxf(acc[0], 0.f)) | ((unsigned)bfu(fmaxf(acc[1], 0.f)) << 16);
    hq.y = (unsigned)bfu(fmaxf(acc[2], 0.f)) | ((unsigned)bfu(fmaxf(acc[3], 0.f)) << 16);
    *my_h = hq;
    f32x4 acc2 = *(const f32x4*)sbf2;
    __syncthreads();
    const bf16x8 h0 = bc8(hbase[0]);
    const bf16x8 h1 = bc8(hbase[64]);
    const bf16x8 h2 = bc8(hbase[128]);
    const bf16x8 h3 = bc8(hbase[192]);

    // ---- matmul2: 4 MFMA
    __builtin_amdgcn_s_setprio(1);
    acc2 = MFMA_BF16(w2r[0], h0, acc2, 0, 0, 0);
    acc2 = MFMA_BF16(w2r[1], h1, acc2, 0, 0, 0);
    acc2 = MFMA_BF16(w2r[2], h2, acc2, 0, 0, 0);
    acc2 = MFMA_BF16(w2r[3], h3, acc2, 0, 0, 0);
    __builtin_amdgcn_s_setprio(0);

    // ---- mode-fused writeback (local r = 0..3, all fp32)
    #pragma unroll
    for (int r = 0; r < 4; ++r) {
        const float k = acc2[r];
        if (M == 1)      U[r] = k;
        else if (M == 2) V[r] = k;
        else if (M == 3) {
            const float u = U[r], v = V[r];
            U[r] = fmaf(3.f, v + k, u);
            V[r] = u - v + k;
        } else {
            y[r] = fmaf(HS * 0.125f, U[r] + k, y[r]);
        }
    }
}

__global__ __launch_bounds__(512) void gnode_kernel(
    const float* __restrict__ x, const uint4* __restrict__ wfr,
    const float* __restrict__ b1, const float* __restrict__ b2,
    const float* __restrict__ bl, float* __restrict__ out, int n)
{
    __shared__ uint4 argx[4][64];    // 4KB: arg B-frag exchange (slot kb)
    __shared__ uint4 hx[4][64];      // 4KB: hidden B-frag exchange
    __shared__ float s_bf[256];      // 1KB: b1 [0..127], b2 [128..255]

    const int tid  = threadIdx.x;
    const int lane = tid & 63;
    const int wid  = tid >> 6;       // 0..7: which 16-out-ch slice (MB = wid)
    const int g    = lane >> 4;
    const int c16  = lane & 15;
    const int row  = blockIdx.x * 16 + c16;   // this lane's batch row
    const int rowc = row < n ? row : n - 1;

    if (tid < 128)      s_bf[tid]       = b1[tid];
    else if (tid < 256) s_bf[tid]       = b2[tid - 128];

    // ---- weights: this wave's MB slice, global kb order (4+4 frags)
    bf16x8 w1r[4], w2r[4];
    #pragma unroll
    for (int kb = 0; kb < 4; ++kb) {
        w1r[kb] = bc8(wfr[(wid * 4 + kb) * 64 + lane]);
        w2r[kb] = bc8(wfr[(32 + wid * 4 + kb) * 64 + lane]);
    }

    // ---- hoisted LDS pointers
    //   own half-frag: slot wid>>1, half wid&1
    uint2*       my_arg = (uint2*)((char*)&argx[wid >> 1][lane] + (wid & 1) * 8);
    uint2*       my_h   = (uint2*)((char*)&hx[wid >> 1][lane] + (wid & 1) * 8);
    const uint4* abase  = &argx[0][lane];   // frag kb at abase[kb*64]
    const uint4* hbase  = &hx[0][lane];
    const float* sbf1   = &s_bf[16 * wid + 4 * g];
    const float* sbf2   = &s_bf[128 + 16 * wid + 4 * g];

    // ---- state: this wave's 4 elems (ch = 16wid + 4g + r)
    float y[4];
    {
        const f32x4 v = ((const f32x4*)x)[(size_t)rowc * 32 + 4 * wid + g];
        #pragma unroll
        for (int r = 0; r < 4; ++r) y[r] = v[r];
    }
    __syncthreads();

    float U[4], V[4];

    #pragma unroll 1
    for (int st = 0; st < 10; ++st) {
        feval<1>(w1r, w2r, sbf1, sbf2, my_arg, abase, my_h, hbase, y, U, V);
        feval<2>(w1r, w2r, sbf1, sbf2, my_arg, abase, my_h, hbase, y, U, V);
        feval<3>(w1r, w2r, sbf1, sbf2, my_arg, abase, my_h, hbase, y, U, V);
        feval<4>(w1r, w2r, sbf1, sbf2, my_arg, abase, my_h, hbase, y, U, V);
    }

    // ---- epilogue: out^T = Wl^T y^T + bl.  All 8 waves publish y quarters;
    //      waves 0..3 compute out MB = wid.
    {
        uint2 yq;
        yq.x = (unsigned)bfu(y[0]) | ((unsigned)bfu(y[1]) << 16);
        yq.y = (unsigned)bfu(y[2]) | ((unsigned)bfu(y[3]) << 16);
        *my_arg = yq;
    }
    __syncthreads();
    if (wid < 4) {
        const bf16x8 yf0 = bc8(abase[0]);
        const bf16x8 yf1 = bc8(abase[64]);
        const bf16x8 yf2 = bc8(abase[128]);
        const bf16x8 yf3 = bc8(abase[192]);
        f32x4 ao = ((const f32x4*)bl)[wid * 4 + g];      // bl[16wid + 4g + r]
        const int fb = 64 + wid * 4;                     // Wl frag base
        ao = MFMA_BF16(bc8(wfr[(fb + 0) * 64 + lane]), yf0, ao, 0, 0, 0);
        ao = MFMA_BF16(bc8(wfr[(fb + 1) * 64 + lane]), yf1, ao, 0, 0, 0);
        ao = MFMA_BF16(bc8(wfr[(fb + 2) * 64 + lane]), yf2, ao, 0, 0, 0);
        ao = MFMA_BF16(bc8(wfr[(fb + 3) * 64 + lane]), yf3, ao, 0, 0, 0);
        if (row < n)
            ((f32x4*)out)[(size_t)row * 16 + wid * 4 + g] = ao;  // out[row][16wid+4g+r]
    }
}

// ---- prep: A-frag-linear bf16 weights into d_ws ----
// A-frag (16x32): lane l, elem j:  row = l&15 (+16*MB),
//                                  k   = 32*kb + 16*(j>>2) + 4*(l>>4) + (j&3)
// wfr[f*64+lane] : f 0..31 = W1 (MB=f>>2,kb=f&3), 32..63 = W2, 64..79 = Wl.
__global__ void prep_kernel(const float* __restrict__ W1, const float* __restrict__ W2,
                            const float* __restrict__ Wl, uint4* __restrict__ wfr)
{
    int t = blockIdx.x * 256 + threadIdx.x;
    if (t >= 80 * 64) return;
    int f = t >> 6, lane = t & 63;
    int gq = lane >> 4, c = lane & 15;
    const float* W; int mb, kv, cols;
    if (f < 32)      { W = W1; mb = f >> 2;        kv = f & 3;        cols = 128; }
    else if (f < 64) { W = W2; mb = (f - 32) >> 2; kv = (f - 32) & 3; cols = 128; }
    else             { W = Wl; mb = (f - 64) >> 2; kv = (f - 64) & 3; cols = 64;  }
    int col = mb * 16 + c;               // output-channel (A row)
    unsigned short v[8];
    #pragma unroll
    for (int j = 0; j < 8; ++j) {
        int k = kv * 32 + (j >> 2) * 16 + gq * 4 + (j & 3);
        v[j] = __builtin_bit_cast(unsigned short, (__bf16)W[k * cols + col]);
    }
    uint4 o;
    o.x = (unsigned)v[0] | ((unsigned)v[1] << 16);
    o.y = (unsigned)v[2] | ((unsigned)v[3] << 16);
    o.z = (unsigned)v[4] | ((unsigned)v[5] << 16);
    o.w = (unsigned)v[6] | ((unsigned)v[7] << 16);
    wfr[t] = o;
}

extern "C" void kernel_launch(void* const* d_in, const int* in_sizes, int n_in,
                              void* d_out, int out_size, void* d_ws, size_t ws_size,
                              hipStream_t stream)
{
    const float* x  = (const float*)d_in[0];
    const float* W1 = (const float*)d_in[1];
    const float* b1 = (const float*)d_in[2];
    const float* W2 = (const float*)d_in[3];
    const float* b2 = (const float*)d_in[4];
    const float* Wl = (const float*)d_in[5];
    const float* bl = (const float*)d_in[6];

    const int n = in_sizes[0] / 128;

    uint4* wfr = (uint4*)d_ws;                       // 80*64*16 = 81920 B

    prep_kernel<<<20, 256, 0, stream>>>(W1, W2, Wl, wfr);

    const int nb = (n + 15) / 16;            // 16 rows per block (8 waves)
    gnode_kernel<<<nb, 512, 0, stream>>>(x, wfr, b1, b2, bl, (float*)d_out, n);
}

// Round 20
// 526.344 us; speedup vs baseline: 1.0192x; 1.0192x over previous
//
#include <hip/hip_runtime.h>
#include <hip/hip_bf16.h>

// GNODE fully fused: y' = relu(y@W1+b1)@W2+b2, RK4(3/8) x10 steps (h=0.1),
// out = y@Wl+bl.  N=200000 rows, 128 ch, 64 out ch.
//
// Round 20: 32x32x16 MFMA variant of r17 (best: 466us, 4-way split).
// Rationale: 32x32 shape is 15% faster per FLOP (m119 2495 vs 2176 TF) and
// covers 32 batch rows/block at the SAME per-row register cost (state 48 +
// acc 16 for 2x rows) -> barriers/VALU per row halved, occupancy unchanged.
// r19's 8-way had 3.2e7 bank conflicts (b64 half-frag writes) - reverted.
//
// Block = 256 thr = 4 waves, 32 rows; wave wid owns out-ch [32wid,+32) of
// both layers (one 32-row M-tile).  Weights 8+8 A-frags = 64 regs (AGPR).
// Layouts (32x32x16 bf16):
//   C/D (HW-verified m74/m101): col(batch) = lane&31,
//        row(ch_local) = (reg&3) + 8*(reg>>2) + 4*(lane>>5), reg in [0,16)
//   A/B operand (derived by the same extension pattern that yields the
//   HW-verified 16x16x32 formula): elem j of 8:
//        k = 16*kw + 8*(j>>2) + 4*(lane>>5) + (j&3)
//   => B-frag window q satisfies frag[q][j] = state[8q+j]  (lane-local, the
//      acc register order IS the state order - identical plumbing to r17).
// Exchange: wave writes its 2 windows (2wid, 2wid+1) as b128, reads other 6;
// all ops lane-contiguous b128 -> conflict-free.  2 barriers/feval on
// alternating buffers (argx, hx) -> WAR-safe.
//
// State recurrences (template<MODE>):
//   M1: U<-k1   M2: V<-k2   M3: U<-U+3(V+k3), V<-U-V+k3   M4: y+=h/8(U+k4)

typedef __attribute__((ext_vector_type(8))) short bf16x8;
typedef __attribute__((ext_vector_type(4))) float f32x4;
typedef __attribute__((ext_vector_type(16))) float f32x16;

constexpr float HS = 0.1f;

__device__ __forceinline__ short bf16s(float f) {
    return __builtin_bit_cast(short, (__bf16)f);      // -> v_cvt_pk_bf16_f32 (paired)
}
__device__ __forceinline__ bf16x8 bc8(uint4 u) { return __builtin_bit_cast(bf16x8, u); }

#define MFMA32 __builtin_amdgcn_mfma_f32_32x32x16_bf16

// B-frag for window t (0/1) from state elems [8t, 8t+8).
template<int M>
__device__ __forceinline__ bf16x8 build_frag(const float (&y)[16], const float (&U)[16],
                                             const float (&V)[16], int t) {
    bf16x8 f;
    #pragma unroll
    for (int j = 0; j < 8; ++j) {
        const int e = t * 8 + j;
        float v;
        if (M == 1)      v = y[e];
        else if (M == 2) v = fmaf(HS * (1.f / 3.f), U[e], y[e]);
        else if (M == 3) v = fmaf(-HS * (1.f / 3.f), U[e], fmaf(HS, V[e], y[e]));
        else             v = fmaf(HS, V[e], y[e]);
        f[j] = bf16s(v);
    }
    return f;
}

// One f-eval for this wave's 32-out-ch slice (32 batch rows).
// Weight frags wid-relative: w[kl] = global window (2wid+kl)&7.
template<int M>
__device__ __forceinline__ void feval(const bf16x8 (&w1r)[8], const bf16x8 (&w2r)[8],
                                      const float* __restrict__ sbf1,
                                      const float* __restrict__ sbf2,
                                      uint4* __restrict__ myA,
                                      const uint4* const (&oa)[6],
                                      uint4* __restrict__ myH,
                                      const uint4* const (&oh)[6],
                                      float (&y)[16], float (&U)[16], float (&V)[16])
{
    // ---- own 2 arg windows -> LDS; bias init overlaps the barrier
    const bf16x8 a0 = build_frag<M>(y, U, V, 0);
    const bf16x8 a1 = build_frag<M>(y, U, V, 1);
    myA[0]  = __builtin_bit_cast(uint4, a0);
    myA[64] = __builtin_bit_cast(uint4, a1);
    f32x16 acc;
    #pragma unroll
    for (int q = 0; q < 4; ++q) {
        const f32x4 b = *(const f32x4*)&sbf1[8 * q];
        #pragma unroll
        for (int r = 0; r < 4; ++r) acc[4 * q + r] = b[r];
    }
    __syncthreads();
    const bf16x8 e2 = bc8(*oa[0]), e3 = bc8(*oa[1]), e4 = bc8(*oa[2]);
    const bf16x8 e5 = bc8(*oa[3]), e6 = bc8(*oa[4]), e7 = bc8(*oa[5]);

    // ---- matmul1: 8 MFMA (windows in wid-relative order)
    __builtin_amdgcn_s_setprio(1);
    acc = MFMA32(w1r[0], a0, acc, 0, 0, 0);
    acc = MFMA32(w1r[1], a1, acc, 0, 0, 0);
    acc = MFMA32(w1r[2], e2, acc, 0, 0, 0);
    acc = MFMA32(w1r[3], e3, acc, 0, 0, 0);
    acc = MFMA32(w1r[4], e4, acc, 0, 0, 0);
    acc = MFMA32(w1r[5], e5, acc, 0, 0, 0);
    acc = MFMA32(w1r[6], e6, acc, 0, 0, 0);
    acc = MFMA32(w1r[7], e7, acc, 0, 0, 0);
    __builtin_amdgcn_s_setprio(0);

    // ---- relu -> own h windows (acc reg order == state order)
    bf16x8 h0, h1;
    #pragma unroll
    for (int j = 0; j < 8; ++j) {
        h0[j] = bf16s(fmaxf(acc[j], 0.f));
        h1[j] = bf16s(fmaxf(acc[8 + j], 0.f));
    }
    myH[0]  = __builtin_bit_cast(uint4, h0);
    myH[64] = __builtin_bit_cast(uint4, h1);
    f32x16 acc2;
    #pragma unroll
    for (int q = 0; q < 4; ++q) {
        const f32x4 b = *(const f32x4*)&sbf2[8 * q];
        #pragma unroll
        for (int r = 0; r < 4; ++r) acc2[4 * q + r] = b[r];
    }
    __syncthreads();
    const bf16x8 f2 = bc8(*oh[0]), f3 = bc8(*oh[1]), f4 = bc8(*oh[2]);
    const bf16x8 f5 = bc8(*oh[3]), f6 = bc8(*oh[4]), f7 = bc8(*oh[5]);

    // ---- matmul2: 8 MFMA
    __builtin_amdgcn_s_setprio(1);
    acc2 = MFMA32(w2r[0], h0, acc2, 0, 0, 0);
    acc2 = MFMA32(w2r[1], h1, acc2, 0, 0, 0);
    acc2 = MFMA32(w2r[2], f2, acc2, 0, 0, 0);
    acc2 = MFMA32(w2r[3], f3, acc2, 0, 0, 0);
    acc2 = MFMA32(w2r[4], f4, acc2, 0, 0, 0);
    acc2 = MFMA32(w2r[5], f5, acc2, 0, 0, 0);
    acc2 = MFMA32(w2r[6], f6, acc2, 0, 0, 0);
    acc2 = MFMA32(w2r[7], f7, acc2, 0, 0, 0);
    __builtin_amdgcn_s_setprio(0);

    // ---- mode-fused writeback (e = reg, all fp32)
    #pragma unroll
    for (int e = 0; e < 16; ++e) {
        const float k = acc2[e];
        if (M == 1)      U[e] = k;
        else if (M == 2) V[e] = k;
        else if (M == 3) {
            const float u = U[e], v = V[e];
            U[e] = fmaf(3.f, v + k, u);
            V[e] = u - v + k;
        } else {
            y[e] = fmaf(HS * 0.125f, U[e] + k, y[e]);
        }
    }
}

__global__ __launch_bounds__(256) void gnode_kernel(
    const float* __restrict__ x, const uint4* __restrict__ wfr,
    const float* __restrict__ b1, const float* __restrict__ b2,
    const float* __restrict__ bl, float* __restrict__ out, int n)
{
    __shared__ uint4 argx[8][64];    // 8KB: arg window exchange
    __shared__ uint4 hx[8][64];      // 8KB: hidden window exchange
    __shared__ float s_bf[256];      // 1KB: b1 [0..127], b2 [128..255]

    const int tid  = threadIdx.x;
    const int lane = tid & 63;
    const int wid  = tid >> 6;       // 0..3: which 32-out-ch slice
    const int hw   = lane >> 5;      // half-wave
    const int c32  = lane & 31;
    const int row  = blockIdx.x * 32 + c32;   // this lane's batch row
    const int rowc = row < n ? row : n - 1;

    s_bf[tid] = (tid < 128) ? b1[tid] : b2[tid - 128];

    // ---- weights: wid-relative window order kl -> (2wid+kl)&7
    bf16x8 w1r[8], w2r[8];
    #pragma unroll
    for (int kl = 0; kl < 8; ++kl) {
        const int kg = (2 * wid + kl) & 7;
        w1r[kl] = bc8(wfr[(wid * 8 + kg) * 64 + lane]);
        w2r[kl] = bc8(wfr[(32 + wid * 8 + kg) * 64 + lane]);
    }

    // ---- hoisted LDS pointers
    uint4* myA = &argx[2 * wid][lane];       // own windows 2wid, 2wid+1
    uint4* myH = &hx[2 * wid][lane];
    const uint4* oa[6];
    const uint4* oh[6];
    #pragma unroll
    for (int kl = 2; kl < 8; ++kl) {
        const int kg = (2 * wid + kl) & 7;
        oa[kl - 2] = &argx[kg][lane];
        oh[kl - 2] = &hx[kg][lane];
    }
    const float* sbf1 = &s_bf[32 * wid + 4 * hw];
    const float* sbf2 = &s_bf[128 + 32 * wid + 4 * hw];

    // ---- state: 16 elems, ch_local = (e&3) + 8*(e>>2) + 4*hw (reg order)
    float y[16];
    {
        const f32x4* x4 = (const f32x4*)x;
        #pragma unroll
        for (int q = 0; q < 4; ++q) {
            const f32x4 v = x4[(size_t)rowc * 32 + 8 * wid + 2 * q + hw];
            #pragma unroll
            for (int r = 0; r < 4; ++r) y[4 * q + r] = v[r];
        }
    }
    __syncthreads();

    float U[16], V[16];

    #pragma unroll 1
    for (int st = 0; st < 10; ++st) {
        feval<1>(w1r, w2r, sbf1, sbf2, myA, oa, myH, oh, y, U, V);
        feval<2>(w1r, w2r, sbf1, sbf2, myA, oa, myH, oh, y, U, V);
        feval<3>(w1r, w2r, sbf1, sbf2, myA, oa, myH, oh, y, U, V);
        feval<4>(w1r, w2r, sbf1, sbf2, myA, oa, myH, oh, y, U, V);
    }

    // ---- epilogue: out^T = Wl^T y^T + bl.  All waves publish y windows;
    //      waves 0,1 compute out-ch [32wid,+32).
    {
        bf16x8 y0, y1;
        #pragma unroll
        for (int j = 0; j < 8; ++j) { y0[j] = bf16s(y[j]); y1[j] = bf16s(y[8 + j]); }
        myA[0]  = __builtin_bit_cast(uint4, y0);
        myA[64] = __builtin_bit_cast(uint4, y1);
    }
    __syncthreads();
    if (wid < 2) {
        f32x16 ao;
        {
            const f32x4* bl4 = (const f32x4*)bl;
            #pragma unroll
            for (int q = 0; q < 4; ++q) {
                const f32x4 b = bl4[8 * wid + 2 * q + hw];
                #pragma unroll
                for (int r = 0; r < 4; ++r) ao[4 * q + r] = b[r];
            }
        }
        #pragma unroll
        for (int kw = 0; kw < 8; ++kw)
            ao = MFMA32(bc8(wfr[(64 + wid * 8 + kw) * 64 + lane]),
                        bc8(argx[kw][lane]), ao, 0, 0, 0);
        if (row < n) {
            f32x4* out4 = (f32x4*)out;
            #pragma unroll
            for (int q = 0; q < 4; ++q) {
                f32x4 v;
                #pragma unroll
                for (int r = 0; r < 4; ++r) v[r] = ao[4 * q + r];
                out4[(size_t)row * 16 + 8 * wid + 2 * q + hw] = v;
            }
        }
    }
}

// ---- prep: A-frag-linear bf16 weights into d_ws (32x32x16 layout) ----
// A-frag (32x16): lane l, elem j: row(out-ch) = MB*32 + (l&31),
//                                 k = kw*16 + 8*(j>>2) + 4*(l>>5) + (j&3)
// wfr[f*64+lane]: f 0..31 = W1 (MB=f>>3, kw=f&7), 32..63 = W2, 64..79 = Wl.
__global__ void prep_kernel(const float* __restrict__ W1, const float* __restrict__ W2,
                            const float* __restrict__ Wl, uint4* __restrict__ wfr)
{
    int t = blockIdx.x * 256 + threadIdx.x;
    if (t >= 80 * 64) return;
    int f = t >> 6, lane = t & 63;
    int hw = lane >> 5, c = lane & 31;
    const float* W; int mb, kw, cols;
    if (f < 32)      { W = W1; mb = f >> 3;        kw = f & 7;        cols = 128; }
    else if (f < 64) { W = W2; mb = (f - 32) >> 3; kw = (f - 32) & 7; cols = 128; }
    else             { W = Wl; mb = (f - 64) >> 3; kw = (f - 64) & 7; cols = 64;  }
    int col = mb * 32 + c;               // output-channel (A row)
    unsigned short v[8];
    #pragma unroll
    for (int j = 0; j < 8; ++j) {
        int k = kw * 16 + 8 * (j >> 2) + 4 * hw + (j & 3);
        v[j] = (unsigned short)__builtin_bit_cast(short, (__bf16)W[k * cols + col]);
    }
    uint4 o;
    o.x = (unsigned)v[0] | ((unsigned)v[1] << 16);
    o.y = (unsigned)v[2] | ((unsigned)v[3] << 16);
    o.z = (unsigned)v[4] | ((unsigned)v[5] << 16);
    o.w = (unsigned)v[6] | ((unsigned)v[7] << 16);
    wfr[t] = o;
}

extern "C" void kernel_launch(void* const* d_in, const int* in_sizes, int n_in,
                              void* d_out, int out_size, void* d_ws, size_t ws_size,
                              hipStream_t stream)
{
    const float* x  = (const float*)d_in[0];
    const float* W1 = (const float*)d_in[1];
    const float* b1 = (const float*)d_in[2];
    const float* W2 = (const float*)d_in[3];
    const float* b2 = (const float*)d_in[4];
    const float* Wl = (const float*)d_in[5];
    const float* bl = (const float*)d_in[6];

    const int n = in_sizes[0] / 128;

    uint4* wfr = (uint4*)d_ws;                       // 80*64*16 = 81920 B

    prep_kernel<<<20, 256, 0, stream>>>(W1, W2, Wl, wfr);

    const int nb = (n + 31) / 32;            // 32 rows per block (4 waves)
    gnode_kernel<<<nb, 256, 0, stream>>>(x, wfr, b1, b2, bl, (float*)d_out, n);
}